// Round 2
// baseline (175.886 us; speedup 1.0000x reference)
//
#include <hip/hip_runtime.h>

#define DIMN 32
#define HD   32
#define FN   16
#define FE   8
#define NG   64
#define NPB1 16   // nodes per block, K1
#define CAP  64   // bucket capacity per dst node (in-degree ~Poisson(16); fallback below)
#define NPW  4    // nodes per wave, K23

// K1: per-node precompute + workspace zeroing (agg, u, deg).
//   out[n,d]   = relu(x[n,:] @ lin0_w[d,:] + lin0_b[d])
//   G[n,h,f]   = sum_d out[n,d] * nn_w[(d*32+h)*8 + f]   (stored n*256 + h*8 + f)
//   bmsg[n,h]  = sum_d out[n,d] * nn_b[d*32+h]
__global__ __launch_bounds__(256) void k1_node_pre(
    const float* __restrict__ x, const float* __restrict__ lin0_w,
    const float* __restrict__ lin0_b, const float* __restrict__ nn_w,
    const float* __restrict__ nn_b,
    float* __restrict__ outn, float* __restrict__ G, float* __restrict__ bmsg,
    float* __restrict__ agg, float* __restrict__ u, int* __restrict__ deg, int N)
{
    __shared__ float s_nnw[DIMN * HD * FE];  // 32 KB; layout d*256 + (h*8+f) -> conflict-free
    __shared__ float s_nnb[DIMN * HD];       // 4 KB
    __shared__ float s_l0w[DIMN * FN];
    __shared__ float s_l0b[DIMN];
    __shared__ float s_out[NPB1 * DIMN];     // 2 KB

    const int tid = threadIdx.x;
    for (int i = tid; i < DIMN * HD * FE; i += 256) s_nnw[i] = nn_w[i];
    for (int i = tid; i < DIMN * HD; i += 256)      s_nnb[i] = nn_b[i];
    for (int i = tid; i < DIMN * FN; i += 256)      s_l0w[i] = lin0_w[i];
    if (tid < DIMN) s_l0b[tid] = lin0_b[tid];

    const int n0 = blockIdx.x * NPB1;

    // Zeroing (replaces memsets): agg slice, deg slice, first 8 blocks zero u.
    {
        const int a0 = n0 * HD;
        const int a1 = min((n0 + NPB1) * HD, N * HD);
        for (int i = a0 + tid; i < a1; i += 256) agg[i] = 0.f;
        if (tid < NPB1 && n0 + tid < N) deg[n0 + tid] = 0;
        if (blockIdx.x < (NG * HD) / 256) u[blockIdx.x * 256 + tid] = 0.f;
    }
    __syncthreads();

    // Phase A: out for all NPB1 nodes (8 nodes in parallel per pass, 32 thr/node).
    #pragma unroll
    for (int pass = 0; pass < 2; ++pass) {
        const int nl = pass * 8 + (tid >> 5);
        const int d  = tid & 31;
        const int n  = n0 + nl;
        if (n < N) {
            float s = s_l0b[d];
            const float* xr = x + (size_t)n * FN;
            #pragma unroll
            for (int j = 0; j < FN; ++j) s = fmaf(xr[j], s_l0w[d * FN + j], s);
            s = fmaxf(s, 0.f);
            s_out[nl * DIMN + d] = s;
            outn[(size_t)n * DIMN + d] = s;
        }
    }
    __syncthreads();

    // Phase B: G rows (s_out broadcast; s_nnw conflict-free; barrier-free).
    for (int nl = 0; nl < NPB1; ++nl) {
        const int n = n0 + nl;
        if (n >= N) break;
        float g = 0.f;
        #pragma unroll 8
        for (int d = 0; d < DIMN; ++d)
            g = fmaf(s_out[nl * DIMN + d], s_nnw[d * 256 + tid], g);
        G[(size_t)n * 256 + tid] = g;
    }

    // Phase B2: bmsg.
    #pragma unroll
    for (int pass = 0; pass < 2; ++pass) {
        const int nl = pass * 8 + (tid >> 5);
        const int h  = tid & 31;
        const int n  = n0 + nl;
        if (n < N) {
            float b = 0.f;
            #pragma unroll 8
            for (int d = 0; d < DIMN; ++d)
                b = fmaf(s_out[nl * DIMN + d], s_nnb[d * HD + h], b);
            bmsg[(size_t)n * HD + h] = b;
        }
    }
}

// Kb: bucket edges by destination. eidx[dst*CAP + pos] = e.
// Overflow (never in practice, P ~ 1e-20 for Poisson(16) > 64): fall back to the
// old atomic-scatter path into agg, which K23 adds in before relu.
__global__ __launch_bounds__(256) void kb_bucket(
    const int* __restrict__ ei, const float* __restrict__ ea,
    const float* __restrict__ G, const float* __restrict__ bmsg,
    int* __restrict__ deg, int* __restrict__ eidx, float* __restrict__ agg, int E)
{
    const int e = blockIdx.x * 256 + threadIdx.x;
    if (e >= E) return;
    const int dst = ei[E + e];
    const int pos = atomicAdd(&deg[dst], 1);
    if (pos < CAP) {
        eidx[dst * CAP + pos] = e;
    } else {
        const int src = ei[e];
        for (int h = 0; h < HD; ++h) {
            float m = bmsg[(size_t)src * HD + h];
            #pragma unroll
            for (int f = 0; f < FE; ++f)
                m = fmaf(ea[(size_t)e * FE + f], G[(size_t)src * 256 + h * FE + f], m);
            atomicAdd(agg + (size_t)dst * HD + h, m);
        }
    }
}

// K23: per dst node, gather in-edges (no atomics), root + relu, run-length pool.
// One wave per NPW consecutive nodes; lane = h + 32*p; the two half-waves process
// edges j = p, p+2, p+4, ... and are combined with one shfl_xor(32).
__global__ __launch_bounds__(256) void k23_gather_upd(
    const int* __restrict__ ei, const float* __restrict__ ea,
    const float* __restrict__ G, const float* __restrict__ bmsg,
    const int* __restrict__ deg, const int* __restrict__ eidx,
    const float* __restrict__ agg, const float* __restrict__ outn,
    const float* __restrict__ root_w, const float* __restrict__ conv_b,
    const int* __restrict__ batch, float* __restrict__ u, int N)
{
    __shared__ float s_rw[DIMN * HD];
    __shared__ float s_cb[HD];
    const int tid = threadIdx.x;
    for (int i = tid; i < DIMN * HD; i += 256) s_rw[i] = root_w[i];
    if (tid < HD) s_cb[tid] = conv_b[tid];
    __syncthreads();

    const int lane  = tid & 63;
    const int h     = lane & 31;
    const int p     = lane >> 5;   // edge parity
    const int wid   = (blockIdx.x * 256 + tid) >> 6;
    const int nbase = wid * NPW;

    float accp  = 0.f;   // pooled run-length accumulator
    int   g_cur = -1;

    for (int i = 0; i < NPW; ++i) {
        const int n = nbase + i;
        if (n >= N) break;

        const int dn = min(deg[n], CAP);
        float acc = 0.f;
        for (int j = p; j < dn; j += 2) {
            const int e   = eidx[n * CAP + j];
            const int src = ei[e];
            const float4 w0 = *(const float4*)(ea + (size_t)e * FE);
            const float4 w1 = *(const float4*)(ea + (size_t)e * FE + 4);
            const float* gp = G + (size_t)src * 256 + h * 8;
            const float4 ga = *(const float4*)(gp);
            const float4 gb = *(const float4*)(gp + 4);
            float m = bmsg[(size_t)src * HD + h];
            m = fmaf(w0.x, ga.x, m);
            m = fmaf(w0.y, ga.y, m);
            m = fmaf(w0.z, ga.z, m);
            m = fmaf(w0.w, ga.w, m);
            m = fmaf(w1.x, gb.x, m);
            m = fmaf(w1.y, gb.y, m);
            m = fmaf(w1.z, gb.z, m);
            m = fmaf(w1.w, gb.w, m);
            acc += m;
        }
        acc += __shfl_xor(acc, 32);   // combine the two parity halves

        // root weight + conv bias + overflow base (agg ~ always zero)
        float v = acc + s_cb[h] + agg[(size_t)n * HD + h];
        const float orow = outn[(size_t)n * DIMN + h];  // lane h holds outn[n,h]
        #pragma unroll
        for (int k = 0; k < DIMN; ++k)
            v = fmaf(__shfl(orow, k, 32), s_rw[k * HD + h], v);
        v = fmaxf(v, 0.f);

        const int g = batch[n];   // uniform across the wave
        if (g != g_cur) {
            if (g_cur >= 0 && p == 0)
                atomicAdd(u + (size_t)g_cur * HD + h, accp);
            g_cur = g;
            accp = v;
        } else {
            accp += v;
        }
    }
    if (g_cur >= 0 && p == 0)
        atomicAdd(u + (size_t)g_cur * HD + h, accp);
}

// K4: head — o = relu(u@lin1_w^T + lin1_b); out = o@lin2_w^T + lin2_b.
__global__ __launch_bounds__(64) void k4_head(
    const float* __restrict__ u, const float* __restrict__ lin1_w,
    const float* __restrict__ lin1_b, const float* __restrict__ lin2_w,
    const float* __restrict__ lin2_b, float* __restrict__ outp)
{
    const int g = threadIdx.x;
    if (g >= NG) return;

    float ur[HD];
    #pragma unroll
    for (int hh = 0; hh < HD; ++hh) ur[hh] = u[(size_t)g * HD + hh];

    float acc = lin2_b[0];
    #pragma unroll
    for (int i = 0; i < 16; ++i) {
        float o = lin1_b[i];
        #pragma unroll
        for (int hh = 0; hh < HD; ++hh)
            o = fmaf(ur[hh], lin1_w[i * HD + hh], o);
        o = fmaxf(o, 0.f);
        acc = fmaf(o, lin2_w[i], acc);
    }
    outp[g] = acc;
}

extern "C" void kernel_launch(void* const* d_in, const int* in_sizes, int n_in,
                              void* d_out, int out_size, void* d_ws, size_t ws_size,
                              hipStream_t stream)
{
    const float* x      = (const float*)d_in[0];
    const int*   ei     = (const int*)  d_in[1];
    const float* ea     = (const float*)d_in[2];
    const int*   batch  = (const int*)  d_in[3];
    const float* lin0_w = (const float*)d_in[4];
    const float* lin0_b = (const float*)d_in[5];
    const float* nn_w   = (const float*)d_in[6];
    const float* nn_b   = (const float*)d_in[7];
    const float* root_w = (const float*)d_in[8];
    const float* conv_b = (const float*)d_in[9];
    const float* lin1_w = (const float*)d_in[10];
    const float* lin1_b = (const float*)d_in[11];
    const float* lin2_w = (const float*)d_in[12];
    const float* lin2_b = (const float*)d_in[13];

    const int N = in_sizes[0] / FN;   // 12500
    const int E = in_sizes[2] / FE;   // 200000

    float* ws   = (float*)d_ws;
    float* outn = ws;                          // N*32
    float* G    = outn + (size_t)N * DIMN;     // N*256
    float* bmsg = G    + (size_t)N * 256;      // N*32
    float* agg  = bmsg + (size_t)N * DIMN;     // N*32 (overflow fallback base)
    float* u    = agg  + (size_t)N * DIMN;     // 64*32
    int*   deg  = (int*)(u + (size_t)NG * HD); // N
    int*   eidx = deg + N;                     // N*CAP

    const int nb1 = (N + NPB1 - 1) / NPB1;     // 782 (>= 8, so u zeroing is covered)
    k1_node_pre<<<nb1, 256, 0, stream>>>(x, lin0_w, lin0_b, nn_w, nn_b,
                                         outn, G, bmsg, agg, u, deg, N);

    const int nbb = (E + 255) / 256;           // 782
    kb_bucket<<<nbb, 256, 0, stream>>>(ei, ea, G, bmsg, deg, eidx, agg, E);

    const int nwaves = (N + NPW - 1) / NPW;    // 3125
    const int nb23   = (nwaves + 3) / 4;       // 782
    k23_gather_upd<<<nb23, 256, 0, stream>>>(ei, ea, G, bmsg, deg, eidx, agg,
                                             outn, root_w, conv_b, batch, u, N);

    k4_head<<<1, 64, 0, stream>>>(u, lin1_w, lin1_b, lin2_w, lin2_b, (float*)d_out);
}